// Round 7
// baseline (402.921 us; speedup 1.0000x reference)
//
#include <hip/hip_runtime.h>

#define BATCH 16
#define CHN   512
#define INTER 64
#define NPIX  2304   // 48*48

typedef _Float16 f16;
typedef _Float16 f16x8 __attribute__((ext_vector_type(8)));
typedef _Float16 f16x4 __attribute__((ext_vector_type(4)));
typedef short    s16x8 __attribute__((ext_vector_type(8)));
typedef float    f32x16 __attribute__((ext_vector_type(16)));

// workspace byte offsets (total 85,590,016 B)
#define XT_OFF   ((size_t)0)          // xT f16  [b][n][c]   16*2304*512
#define QT_OFF   ((size_t)37748736)   // qT f16  [b][n][64]
#define KT_OFF   ((size_t)42467328)   // kT f16  [b][n][64]
#define VB_OFF   ((size_t)47185920)   // v  bf16 [b][c][m]   16*512*2304
#define WHQ_OFF  ((size_t)84934656)   // Wq f16  [64][512]
#define WHK_OFF  ((size_t)85000192)   // Wk f16  [64][512]
#define WHV_OFF  ((size_t)85065728)   // Wv f16  [512][512]

__device__ inline unsigned short f2bf(float f) {
    unsigned int u = __float_as_uint(f);
    unsigned int r = (u + 0x7FFFu + ((u >> 16) & 1u)) >> 16;
    return (unsigned short)r;
}

// pack two fp32 -> (bf16(a) | bf16(b)<<16), round-half-up via +0x8000 then v_perm
__device__ inline unsigned pack_bf16(float a, float b) {
    unsigned ua = __float_as_uint(a) + 0x8000u;
    unsigned ub = __float_as_uint(b) + 0x8000u;
    return __builtin_amdgcn_perm(ub, ua, 0x07060302u);
}

// Lane-half swap between two VGPRs (HW-verified correct in rounds 4/5/6).
__device__ inline void swap32(unsigned x, unsigned y, unsigned& nx, unsigned& ny, int lh) {
#if __has_builtin(__builtin_amdgcn_permlane32_swap)
    auto r = __builtin_amdgcn_permlane32_swap(x, y, false, false);
    nx = r[0]; ny = r[1];
#else
    const unsigned xs = (unsigned)__shfl_xor((int)x, 32, 64);
    const unsigned ys = (unsigned)__shfl_xor((int)y, 32, 64);
    nx = lh ? ys : x;
    ny = lh ? y  : xs;
#endif
}

// async global->LDS DMA, 16 B per lane; LDS dest = wave-uniform base + lane*16
__device__ __forceinline__ void async16(void* lds, const void* g) {
    __builtin_amdgcn_global_load_lds(
        (const __attribute__((address_space(1))) unsigned int*)g,
        (__attribute__((address_space(3))) unsigned int*)lds,
        16, 0, 0);
}

// ---------------------------------------------------------------------------
// x [b][c][n] fp32  ->  xT [b][n][c] f16   (64x64 LDS tile transpose)
// ---------------------------------------------------------------------------
__global__ __launch_bounds__(256) void convert_x_kernel(
    const float* __restrict__ x, f16* __restrict__ xT)
{
    const int n0 = blockIdx.x * 64;
    const int c0 = blockIdx.y * 64;
    const int b  = blockIdx.z;
    const int t  = threadIdx.x;

    __shared__ float tile[64][65];

    {
        const int cr   = t >> 2;
        const int ncol = (t & 3) * 16;
        const float* src = x + ((size_t)b * CHN + (size_t)(c0 + cr)) * NPIX + n0 + ncol;
        #pragma unroll
        for (int u = 0; u < 4; ++u) {
            const float4 v4 = *(const float4*)(src + u * 4);
            tile[cr][ncol + u * 4 + 0] = v4.x;
            tile[cr][ncol + u * 4 + 1] = v4.y;
            tile[cr][ncol + u * 4 + 2] = v4.z;
            tile[cr][ncol + u * 4 + 3] = v4.w;
        }
    }
    __syncthreads();
    #pragma unroll
    for (int r = 0; r < 2; ++r) {
        const int id = t + r * 256;
        const int n  = id >> 3;
        const int cg = id & 7;
        f16x8 o;
        #pragma unroll
        for (int j = 0; j < 8; ++j) o[j] = (f16)tile[cg * 8 + j][n];
        *(f16x8*)(xT + ((size_t)b * NPIX + (size_t)(n0 + n)) * CHN + c0 + cg * 8) = o;
    }
}

// ---------------------------------------------------------------------------
// W fp32 -> f16. grid (256, 3), block 256.
// ---------------------------------------------------------------------------
__global__ __launch_bounds__(256) void convert_w_kernel(
    const float* __restrict__ Wq, const float* __restrict__ Wk,
    const float* __restrict__ Wv, f16* __restrict__ whq,
    f16* __restrict__ whk, f16* __restrict__ whv)
{
    const int which = blockIdx.y;
    const float* src; f16* dst; int count;
    if (which == 0)      { src = Wq; dst = whq; count = 64 * 512; }
    else if (which == 1) { src = Wk; dst = whk; count = 64 * 512; }
    else                 { src = Wv; dst = whv; count = 512 * 512; }
    const int i = (blockIdx.x * 256 + threadIdx.x) * 4;
    if (i < count) {
        const float4 v4 = *(const float4*)(src + i);
        f16x4 o;
        o[0] = (f16)v4.x; o[1] = (f16)v4.y; o[2] = (f16)v4.z; o[3] = (f16)v4.w;
        *(f16x4*)(dst + i) = o;
    }
}

// ---------------------------------------------------------------------------
// Fused projection: virtual weight [Wq;Wk;Wv] (640 rows) x xT.
// grid (18 n-tiles(128), 5 row-tiles(128), 16 b), block 256.  (unchanged R6)
// ---------------------------------------------------------------------------
__global__ __launch_bounds__(256, 2) void proj_kernel(
    const f16* __restrict__ xT, const f16* __restrict__ whq,
    const f16* __restrict__ whk, const f16* __restrict__ whv,
    f16* __restrict__ qTo, f16* __restrict__ kTo,
    unsigned short* __restrict__ vout)
{
    const int nt = blockIdx.x;
    const int rt = blockIdx.y;
    const int b  = blockIdx.z;
    const int t  = threadIdx.x;
    const int wave = t >> 6, lane = t & 63;
    const int row = lane & 31, lh = lane >> 5;

    __shared__ f16 wsm[128][72];
    __shared__ f16 xs[128][72];

    f32x16 acc[4];
    #pragma unroll
    for (int s = 0; s < 4; ++s)
        #pragma unroll
        for (int r = 0; r < 16; ++r) acc[s][r] = 0.0f;

    for (int c0 = 0; c0 < CHN; c0 += 64) {
        __syncthreads();
        #pragma unroll
        for (int r = 0; r < 4; ++r) {
            const int id = t + r * 256;     // 1024 8-elem chunks
            const int co = id >> 3, cg = id & 7;
            const f16* src;
            if (rt == 0) src = (co < 64) ? (whq + (size_t)co * CHN)
                                         : (whk + (size_t)(co - 64) * CHN);
            else         src = whv + (size_t)((rt - 1) * 128 + co) * CHN;
            *(f16x8*)&wsm[co][cg * 8] = *(const f16x8*)(src + c0 + cg * 8);
        }
        #pragma unroll
        for (int r = 0; r < 4; ++r) {
            const int id = t + r * 256;
            const int n = id >> 3, cg = id & 7;
            *(f16x8*)&xs[n][cg * 8] =
                *(const f16x8*)(xT + ((size_t)b * NPIX + (size_t)(nt * 128 + n)) * CHN + c0 + cg * 8);
        }
        __syncthreads();

        #pragma unroll
        for (int kk = 0; kk < 64; kk += 16) {
            const f16x8 bf = *(const f16x8*)&xs[wave * 32 + row][kk + lh * 8];
            #pragma unroll
            for (int cs = 0; cs < 4; ++cs) {
                const f16x8 af = *(const f16x8*)&wsm[cs * 32 + row][kk + lh * 8];
                acc[cs] = __builtin_amdgcn_mfma_f32_32x32x16_f16(af, bf, acc[cs], 0, 0, 0);
            }
        }
    }

    const int n = nt * 128 + wave * 32 + row;
    if (rt == 0) {
        #pragma unroll
        for (int cs = 0; cs < 4; ++cs)
            #pragma unroll
            for (int r = 0; r < 16; ++r) {
                const int i = cs * 32 + (r & 3) + 8 * (r >> 2) + 4 * lh;
                const f16 val = (f16)acc[cs][r];
                if (i < 64) qTo[((size_t)b * NPIX + n) * INTER + i] = val;
                else        kTo[((size_t)b * NPIX + n) * INTER + i - 64] = val;
            }
    } else {
        #pragma unroll
        for (int cs = 0; cs < 4; ++cs)
            #pragma unroll
            for (int r = 0; r < 16; ++r) {
                const int c = (rt - 1) * 128 + cs * 32 + (r & 3) + 8 * (r >> 2) + 4 * lh;
                vout[((size_t)b * CHN + c) * NPIX + n] = f2bf(acc[cs][r]);
            }
    }
}

// ---------------------------------------------------------------------------
// Attention v7: block = 256 n x 128 c, 4 waves; wave owns 64 n x ALL 128 c.
//  - Each va LDS read now feeds 2 MFMA (2 n-strips) and k-frag reads are
//    hoisted across n-strips: 24 LDS reads/wave feed 48 MFMA (R6 was 24:24).
//  - Staging via global_load_lds width-16 DMA: zero ds_writes, zero staging
//    VGPRs. Lane's global source chunk is permuted ((lane&7)^(lane>>3)) so
//    the implicit "base + lane*16" LDS dest reproduces the XOR-swizzled
//    layout the fragment reads expect (permutation stays within one 128 B
//    row -> coalescing unchanged).
//  - One barrier/iter; DMA for it+1 issued at top of iter it (nxt buffer),
//    __syncthreads' vmcnt drain completes it.
// grid (9 n-tiles, 4 c-quarters, 16 b) = 576 blocks, block 256.
// ---------------------------------------------------------------------------
__global__ __launch_bounds__(256, 2) void attn_kernel(
    const float* __restrict__ x, const float* __restrict__ gamma,
    const f16* __restrict__ qT, const f16* __restrict__ kT,
    const unsigned short* __restrict__ vglob, float* __restrict__ out)
{
    const int nt = blockIdx.x;    // 256-n tile
    const int cq = blockIdx.y;    // 128-c quarter
    const int b  = blockIdx.z;
    const int t  = threadIdx.x;
    const int wave = t >> 6, lane = t & 63;
    const int row = lane & 31, lh = lane >> 5;

    __shared__ short vbuf[2][128 * 64];   // [buf][c][m-chunk swizzled] 32 KB
    __shared__ f16   kbuf[2][64 * 64];    // [buf][m][i-chunk swizzled] 16 KB

    const unsigned short* vq = vglob + ((size_t)b * CHN + (size_t)cq * 128) * NPIX;
    const f16* kb = kT + (size_t)b * NPIX * INTER;

    // DMA source addressing: lane ell fills LDS slot base+ell*16, which in the
    // swizzled layout holds row (w*8 + (ell>>3)) chunk ((ell&7)^(ell>>3)).
    const int l3 = lane >> 3;        // row within wave's 8-row group
    const int pc = (lane & 7) ^ l3;  // permuted source chunk
    const unsigned short* vsrc = vq + (size_t)(wave * 8 + l3) * NPIX + pc * 8;
    const f16*            ksrc = kb + (size_t)(wave * 8 + l3) * INTER + pc * 8;

    const int xorv = row & 7;        // fragment-read chunk swizzle

    // q fragments: resident; wave owns 64 n as two 32-n strips
    f16x8 qf[2][4];
    #pragma unroll
    for (int ns = 0; ns < 2; ++ns) {
        const f16* qrow = qT + ((size_t)b * NPIX
                          + (size_t)(nt * 256 + wave * 64 + ns * 32 + row)) * INTER + lh * 8;
        #pragma unroll
        for (int k0 = 0; k0 < 4; ++k0) qf[ns][k0] = *(const f16x8*)(qrow + k0 * 16);
    }

    // ---- prologue: DMA tile 0 into buf 0
    #pragma unroll
    for (int j = 0; j < 4; ++j)
        async16(&vbuf[0][(j * 32 + wave * 8) * 64], vsrc + (size_t)(j * 32) * NPIX);
    #pragma unroll
    for (int j = 0; j < 2; ++j)
        async16(&kbuf[0][(j * 32 + wave * 8) * 64], ksrc + (size_t)(j * 32) * INTER);
    __syncthreads();

    f32x16 accv[8];   // [cs*2+ns] : (32 c) x (32 n)
    #pragma unroll
    for (int s = 0; s < 8; ++s)
        #pragma unroll
        for (int r = 0; r < 16; ++r) accv[s][r] = 0.0f;

    float lrun[2] = {0.0f, 0.0f};
    union PB { unsigned u[4]; s16x8 v; };

    for (int it = 0; it < NPIX / 64; ++it) {
        const int cur = it & 1, nxt = cur ^ 1;
        const int m1 = (it < NPIX / 64 - 1) ? (it + 1) * 64 : 0;  // last: dummy

        // ---- async DMA tile it+1 into nxt (completes at this iter's barrier)
        #pragma unroll
        for (int j = 0; j < 4; ++j)
            async16(&vbuf[nxt][(j * 32 + wave * 8) * 64],
                    vsrc + (size_t)(j * 32) * NPIX + m1);
        #pragma unroll
        for (int j = 0; j < 2; ++j)
            async16(&kbuf[nxt][(j * 32 + wave * 8) * 64],
                    ksrc + (size_t)(m1 + j * 32) * INTER);

        // ---- QK^T both m-halves x both n-strips; k-frags hoisted across ns
        PB pb[2][4];   // [ns][kk]
        #pragma unroll
        for (int mh = 0; mh < 2; ++mh) {
            f16x8 af[4];
            #pragma unroll
            for (int k0 = 0; k0 < 4; ++k0)
                af[k0] = *(const f16x8*)&kbuf[cur][(mh * 32 + row) * 64
                            + (((k0 * 2 + lh) ^ xorv) * 8)];
            #pragma unroll
            for (int ns = 0; ns < 2; ++ns) {
                f32x16 sacc;
                #pragma unroll
                for (int r = 0; r < 16; ++r) sacc[r] = 0.0f;
                #pragma unroll
                for (int k0 = 0; k0 < 4; ++k0)
                    sacc = __builtin_amdgcn_mfma_f32_32x32x16_f16(af[k0], qf[ns][k0], sacc, 0, 0, 0);
                float lp = 0.0f;
                unsigned pg[8];
                #pragma unroll
                for (int tt = 0; tt < 8; ++tt) {
                    const float p0 = __expf(sacc[2 * tt + 0]);
                    const float p1 = __expf(sacc[2 * tt + 1]);
                    lp += p0 + p1;
                    pg[tt] = pack_bf16(p0, p1);
                }
                lrun[ns] += lp;
                #pragma unroll
                for (int half = 0; half < 2; ++half)
                    #pragma unroll
                    for (int p = 0; p < 2; ++p) {
                        unsigned nx, ny;
                        swap32(pg[half * 4 + p], pg[half * 4 + 2 + p], nx, ny, lh);
                        pb[ns][2 * mh + half].u[p]     = nx;
                        pb[ns][2 * mh + half].u[p + 2] = ny;
                    }
            }
        }

        // ---- PV: each va read feeds both n-strips (2 MFMA per LDS read)
        #pragma unroll
        for (int cs = 0; cs < 4; ++cs)
            #pragma unroll
            for (int kk = 0; kk < 4; ++kk) {
                const s16x8 va = *(const s16x8*)&vbuf[cur][(cs * 32 + row) * 64
                                    + (((kk * 2 + lh) ^ xorv) * 8)];
                #pragma unroll
                for (int ns = 0; ns < 2; ++ns)
                    accv[cs * 2 + ns] = __builtin_amdgcn_mfma_f32_32x32x16_bf16(
                        va, pb[ns][kk].v, accv[cs * 2 + ns], 0, 0, 0);
            }

        __syncthreads();   // cur readers done + all waves' nxt DMAs drained
    }

    // ---- epilogue: l combine (lane-half pair covers all 64 m), out = g*acc/l + x
    const float g = gamma[0];
    float linv[2];
    #pragma unroll
    for (int ns = 0; ns < 2; ++ns)
        linv[ns] = 1.0f / (lrun[ns] + __shfl_xor(lrun[ns], 32, 64));

    #pragma unroll
    for (int cs = 0; cs < 4; ++cs)
        #pragma unroll
        for (int ns = 0; ns < 2; ++ns) {
            const int n = nt * 256 + wave * 64 + ns * 32 + row;
            #pragma unroll
            for (int r = 0; r < 16; ++r) {
                const int c = cq * 128 + cs * 32 + (r & 3) + 8 * (r >> 2) + 4 * lh;
                const size_t idx = ((size_t)b * CHN + c) * NPIX + n;
                out[idx] = g * accv[cs * 2 + ns][r] * linv[ns] + x[idx];
            }
        }
}

// ---------------------------------------------------------------------------
extern "C" void kernel_launch(void* const* d_in, const int* in_sizes, int n_in,
                              void* d_out, int out_size, void* d_ws, size_t ws_size,
                              hipStream_t stream) {
    (void)in_sizes; (void)n_in; (void)out_size; (void)ws_size;
    const float* x     = (const float*)d_in[0];
    const float* Wq    = (const float*)d_in[1];
    const float* Wk    = (const float*)d_in[2];
    const float* Wv    = (const float*)d_in[3];
    const float* gamma = (const float*)d_in[4];
    float* out = (float*)d_out;
    char* ws = (char*)d_ws;

    f16* xT  = (f16*)(ws + XT_OFF);
    f16* qTp = (f16*)(ws + QT_OFF);
    f16* kTp = (f16*)(ws + KT_OFF);
    unsigned short* vb = (unsigned short*)(ws + VB_OFF);
    f16* whq = (f16*)(ws + WHQ_OFF);
    f16* whk = (f16*)(ws + WHK_OFF);
    f16* whv = (f16*)(ws + WHV_OFF);

    convert_x_kernel<<<dim3(36, 8, 16), 256, 0, stream>>>(x, xT);
    convert_w_kernel<<<dim3(256, 3, 1), 256, 0, stream>>>(Wq, Wk, Wv, whq, whk, whv);
    proj_kernel<<<dim3(18, 5, 16), 256, 0, stream>>>(xT, whq, whk, whv, qTp, kTp, vb);
    attn_kernel<<<dim3(9, 4, 16), 256, 0, stream>>>(x, gamma, qTp, kTp, vb, out);
}